// Round 1
// baseline (973.857 us; speedup 1.0000x reference)
//
#include <hip/hip_runtime.h>
#include <hip/hip_bf16.h>
#include <type_traits>

typedef __bf16 bf16x8 __attribute__((ext_vector_type(8)));
typedef float f32x4 __attribute__((ext_vector_type(4)));
typedef __hip_bfloat16 bf16;

static constexpr int BB = 2, SEQ = 2048, HID = 2048, LAT = 512, NHEAD = 16;
static constexpr int HD = 128, RD = 64, DQK = 192;
static constexpr int MR = BB * SEQ;  // 4096 rows

__device__ __forceinline__ float bf2f(bf16 x) { return __bfloat162float(x); }
__device__ __forceinline__ bf16 f2bf(float x) { return __float2bfloat16(x); }

// ---------------- fp32 -> bf16 elementwise ----------------
__global__ void k_cvt(const float* __restrict__ in, bf16* __restrict__ out, int n4) {
  int i = blockIdx.x * 256 + threadIdx.x;
  if (i >= n4) return;
  float4 v = reinterpret_cast<const float4*>(in)[i];
  bf16* o = out + (size_t)i * 4;
  o[0] = f2bf(v.x); o[1] = f2bf(v.y); o[2] = f2bf(v.z); o[3] = f2bf(v.w);
}

// ---------------- transpose+convert: W[K][N] f32 -> WT[N][K] bf16 ----------------
__global__ void k_transpose_cvt(const float* __restrict__ W, bf16* __restrict__ WT,
                                int K, int N) {
  __shared__ float t[32][33];
  int k0 = blockIdx.y * 32, n0 = blockIdx.x * 32;
  int c = threadIdx.x & 31, r0 = threadIdx.x >> 5;  // 256 threads, 8 rows/pass
#pragma unroll
  for (int i = 0; i < 32; i += 8) t[r0 + i][c] = W[(size_t)(k0 + r0 + i) * N + n0 + c];
  __syncthreads();
#pragma unroll
  for (int i = 0; i < 32; i += 8)
    WT[(size_t)(n0 + r0 + i) * K + k0 + c] = f2bf(t[c][r0 + i]);
}

// ---------------- V transpose: vflat[b*S+s][h*128+d] -> vt[bh][d][s] ----------------
__global__ void k_transpose_v(const bf16* __restrict__ vflat, bf16* __restrict__ vt) {
  __shared__ bf16 t[32][34];
  int bh = blockIdx.z, b = bh >> 4, hh = bh & 15;
  int s0 = blockIdx.y * 32, d0 = blockIdx.x * 32;
  int c = threadIdx.x & 31, r0 = threadIdx.x >> 5;
#pragma unroll
  for (int i = 0; i < 32; i += 8)
    t[r0 + i][c] = vflat[((size_t)b * SEQ + s0 + r0 + i) * HID + hh * HD + d0 + c];
  __syncthreads();
#pragma unroll
  for (int i = 0; i < 32; i += 8)
    vt[((size_t)bh * HD + d0 + r0 + i) * SEQ + s0 + c] = t[c][r0 + i];
}

// ---------------- RoPE tables ----------------
__global__ void k_rope_tables(float* __restrict__ cosT, float* __restrict__ sinT) {
  int idx = blockIdx.x * 256 + threadIdx.x;  // SEQ*32
  int s = idx >> 5, j = idx & 31;
  float freq = powf(10000.0f, -(float)(2 * j) / 64.0f);
  float a = (float)s * freq;
  cosT[idx] = cosf(a);
  sinT[idx] = sinf(a);
}

// ---------------- GEMM: C[M][N] = A[M][K] * BT[N][K]^T, bf16 in ----------------
template <int BM, int BN, typename OutT>
__global__ __launch_bounds__((BM / 64) * (BN / 64) * 64)
void k_gemm_bt(const bf16* __restrict__ A, const bf16* __restrict__ BT,
               OutT* __restrict__ C, int M, int N, int K) {
  constexpr int BK = 32, LDK = 40;
  constexpr int WN = BN / 64, NW = (BM / 64) * WN, NT = NW * 64;
  __shared__ alignas(16) bf16 As[BM][LDK];
  __shared__ alignas(16) bf16 Bs[BN][LDK];
  const int tid = threadIdx.x, wave = tid >> 6, lane = tid & 63;
  const int lr = lane & 15, lk = lane >> 4;
  const int wm = (wave / WN) * 64, wn = (wave % WN) * 64;
  const int m0 = blockIdx.y * BM, n0 = blockIdx.x * BN;
  f32x4 acc[4][4] = {};
  for (int kt = 0; kt < K; kt += BK) {
    for (int c = tid; c < BM * BK / 8; c += NT) {
      int r = c >> 2, kk = (c & 3) * 8;
      *reinterpret_cast<int4*>(&As[r][kk]) =
          *reinterpret_cast<const int4*>(&A[(size_t)(m0 + r) * K + kt + kk]);
    }
    for (int c = tid; c < BN * BK / 8; c += NT) {
      int r = c >> 2, kk = (c & 3) * 8;
      *reinterpret_cast<int4*>(&Bs[r][kk]) =
          *reinterpret_cast<const int4*>(&BT[(size_t)(n0 + r) * K + kt + kk]);
    }
    __syncthreads();
    bf16x8 af[4], bfr[4];
#pragma unroll
    for (int i = 0; i < 4; i++)
      af[i] = *reinterpret_cast<const bf16x8*>(&As[wm + i * 16 + lr][lk * 8]);
#pragma unroll
    for (int j = 0; j < 4; j++)
      bfr[j] = *reinterpret_cast<const bf16x8*>(&Bs[wn + j * 16 + lr][lk * 8]);
#pragma unroll
    for (int i = 0; i < 4; i++)
#pragma unroll
      for (int j = 0; j < 4; j++)
        acc[i][j] = __builtin_amdgcn_mfma_f32_16x16x32_bf16(af[i], bfr[j], acc[i][j], 0, 0, 0);
    __syncthreads();
  }
#pragma unroll
  for (int i = 0; i < 4; i++)
#pragma unroll
    for (int j = 0; j < 4; j++) {
      int row = m0 + wm + i * 16 + lk * 4, col = n0 + wn + j * 16 + lr;
#pragma unroll
      for (int r = 0; r < 4; r++) {
        float v = acc[i][j][r];
        if constexpr (std::is_same<OutT, float>::value)
          C[(size_t)(row + r) * N + col] = v;
        else
          C[(size_t)(row + r) * N + col] = f2bf(v);
      }
    }
}

// ---------------- assemble q / k (concat + RoPE) ----------------
__global__ void k_assemble_q(const bf16* __restrict__ qc, const bf16* __restrict__ qrr,
                             const float* __restrict__ cosT, const float* __restrict__ sinT,
                             bf16* __restrict__ qbuf) {
  size_t idx = (size_t)blockIdx.x * 256 + threadIdx.x;
  int d = (int)(idx % DQK);
  size_t t = idx / DQK;
  int s = (int)(t % SEQ); t /= SEQ;
  int hh = (int)(t % NHEAD);
  int b = (int)(t / NHEAD);
  size_t row = (size_t)b * SEQ + s;
  bf16 v;
  if (d < HD) {
    v = qc[row * HID + hh * HD + d];
  } else {
    int dd = d - HD, j = dd >> 1;
    float cs = cosT[s * 32 + j], sn = sinT[s * 32 + j];
    float x0 = bf2f(qrr[row * (RD * NHEAD) + hh * RD + 2 * j]);
    float x1 = bf2f(qrr[row * (RD * NHEAD) + hh * RD + 2 * j + 1]);
    v = f2bf((dd & 1) ? (x1 * cs + x0 * sn) : (x0 * cs - x1 * sn));
  }
  qbuf[idx] = v;
}

__global__ void k_assemble_k(const bf16* __restrict__ kc, const bf16* __restrict__ krr,
                             const float* __restrict__ cosT, const float* __restrict__ sinT,
                             bf16* __restrict__ kbuf) {
  size_t idx = (size_t)blockIdx.x * 256 + threadIdx.x;
  int d = (int)(idx % DQK);
  size_t t = idx / DQK;
  int s = (int)(t % SEQ); t /= SEQ;
  int hh = (int)(t % NHEAD);
  int b = (int)(t / NHEAD);
  size_t row = (size_t)b * SEQ + s;
  bf16 v;
  if (d < HD) {
    v = kc[row * HID + hh * HD + d];
  } else {
    int dd = d - HD, j = dd >> 1;
    float cs = cosT[s * 32 + j], sn = sinT[s * 32 + j];
    float x0 = bf2f(krr[row * RD + 2 * j]);
    float x1 = bf2f(krr[row * RD + 2 * j + 1]);
    v = f2bf((dd & 1) ? (x1 * cs + x0 * sn) : (x0 * cs - x1 * sn));
  }
  kbuf[idx] = v;
}

// ---------------- causal flash attention ----------------
// Q,K: [bh][S][192]; VT: [bh][128][S]; Of: [b*S+s][h*128+d] all bf16
__global__ __launch_bounds__(256)
void k_attn(const bf16* __restrict__ Q, const bf16* __restrict__ Kb,
            const bf16* __restrict__ VT, bf16* __restrict__ Of) {
  constexpr int QB = 64, KBL = 64;
  constexpr int LDKS = DQK + 8;  // 200
  constexpr int LDV = KBL + 8;   // 72
  __shared__ alignas(16) bf16 Ks[KBL][LDKS];
  __shared__ alignas(16) bf16 Vs[HD][LDV];
  __shared__ alignas(16) bf16 Ps[4][16][LDV];
  const int qt = blockIdx.x, bh = blockIdx.y;
  const int b = bh >> 4, hh = bh & 15;
  const int tid = threadIdx.x, wave = tid >> 6, lane = tid & 63;
  const int lr = lane & 15, lk = lane >> 4;
  const int q0 = qt * QB;
  const float scale = 0.07216878364870323f;  // 1/sqrt(192)

  const bf16* Qp = Q + ((size_t)bh * SEQ + q0 + wave * 16 + lr) * DQK;
  bf16x8 qf[6];
#pragma unroll
  for (int c = 0; c < 6; c++)
    qf[c] = *reinterpret_cast<const bf16x8*>(Qp + c * 32 + lk * 8);

  f32x4 oacc[8] = {};
  float mrow[4], lrow[4];
#pragma unroll
  for (int r = 0; r < 4; r++) { mrow[r] = -INFINITY; lrow[r] = 0.f; }

  const int nkt = qt + 1;
  for (int kt = 0; kt < nkt; kt++) {
    const int k0 = kt * KBL;
    for (int c = tid; c < KBL * DQK / 8; c += 256) {
      int r = c / (DQK / 8), kk = (c % (DQK / 8)) * 8;
      *reinterpret_cast<int4*>(&Ks[r][kk]) =
          *reinterpret_cast<const int4*>(&Kb[((size_t)bh * SEQ + k0 + r) * DQK + kk]);
    }
    for (int c = tid; c < HD * KBL / 8; c += 256) {
      int r = c >> 3, kk = (c & 7) * 8;
      *reinterpret_cast<int4*>(&Vs[r][kk]) =
          *reinterpret_cast<const int4*>(&VT[((size_t)bh * HD + r) * SEQ + k0 + kk]);
    }
    __syncthreads();

    f32x4 sc[4] = {};
#pragma unroll
    for (int cb = 0; cb < 4; cb++)
#pragma unroll
      for (int c = 0; c < 6; c++) {
        bf16x8 kf = *reinterpret_cast<const bf16x8*>(&Ks[cb * 16 + lr][c * 32 + lk * 8]);
        sc[cb] = __builtin_amdgcn_mfma_f32_16x16x32_bf16(qf[c], kf, sc[cb], 0, 0, 0);
      }

    const bool maskit = (kt == qt);
    float p[4][4], tm[4];
#pragma unroll
    for (int r = 0; r < 4; r++) tm[r] = -INFINITY;
#pragma unroll
    for (int cb = 0; cb < 4; cb++) {
      const int kcg = k0 + cb * 16 + lr;
#pragma unroll
      for (int r = 0; r < 4; r++) {
        float v = sc[cb][r] * scale;
        if (maskit && kcg > q0 + wave * 16 + lk * 4 + r) v = -INFINITY;
        p[cb][r] = v;
        tm[r] = fmaxf(tm[r], v);
      }
    }
#pragma unroll
    for (int m = 1; m < 16; m <<= 1)
#pragma unroll
      for (int r = 0; r < 4; r++) tm[r] = fmaxf(tm[r], __shfl_xor(tm[r], m, 16));

    float rs[4];
#pragma unroll
    for (int r = 0; r < 4; r++) {
      float mn = fmaxf(mrow[r], tm[r]);
      float al = __expf(mrow[r] - mn);
      mrow[r] = mn;
      lrow[r] *= al;
#pragma unroll
      for (int ocb = 0; ocb < 8; ocb++) oacc[ocb][r] *= al;
      float ssum = 0.f;
#pragma unroll
      for (int cb = 0; cb < 4; cb++) {
        float e = __expf(p[cb][r] - mn);
        p[cb][r] = e;
        ssum += e;
      }
      rs[r] = ssum;
    }
#pragma unroll
    for (int m = 1; m < 16; m <<= 1)
#pragma unroll
      for (int r = 0; r < 4; r++) rs[r] += __shfl_xor(rs[r], m, 16);
#pragma unroll
    for (int r = 0; r < 4; r++) lrow[r] += rs[r];

#pragma unroll
    for (int cb = 0; cb < 4; cb++)
#pragma unroll
      for (int r = 0; r < 4; r++)
        Ps[wave][lk * 4 + r][cb * 16 + lr] = f2bf(p[cb][r]);
    __syncthreads();

#pragma unroll
    for (int kk = 0; kk < 2; kk++) {
      bf16x8 pa = *reinterpret_cast<const bf16x8*>(&Ps[wave][lr][kk * 32 + lk * 8]);
#pragma unroll
      for (int ocb = 0; ocb < 8; ocb++) {
        bf16x8 vb = *reinterpret_cast<const bf16x8*>(&Vs[ocb * 16 + lr][kk * 32 + lk * 8]);
        oacc[ocb] = __builtin_amdgcn_mfma_f32_16x16x32_bf16(pa, vb, oacc[ocb], 0, 0, 0);
      }
    }
    __syncthreads();
  }

#pragma unroll
  for (int ocb = 0; ocb < 8; ocb++)
#pragma unroll
    for (int r = 0; r < 4; r++) {
      int qr = q0 + wave * 16 + lk * 4 + r;
      float v = oacc[ocb][r] / lrow[r];
      Of[((size_t)b * SEQ + qr) * HID + hh * HD + ocb * 16 + lr] = f2bf(v);
    }
}

// ---------------- host launch ----------------
extern "C" void kernel_launch(void* const* d_in, const int* in_sizes, int n_in,
                              void* d_out, int out_size, void* d_ws, size_t ws_size,
                              hipStream_t stream) {
  const float* h    = (const float*)d_in[0];
  const float* Wdkv = (const float*)d_in[1];
  const float* Wuk  = (const float*)d_in[2];
  const float* Wkr  = (const float*)d_in[3];
  const float* Wuv  = (const float*)d_in[4];
  const float* Wdq  = (const float*)d_in[5];
  const float* Wuq  = (const float*)d_in[6];
  const float* Wqr  = (const float*)d_in[7];
  const float* Wo   = (const float*)d_in[8];
  float* out = (float*)d_out;

  char* w = (char*)d_ws;
  auto alloc = [&](size_t elems) {
    bf16* p = (bf16*)w;
    w += (elems * sizeof(bf16) + 255) & ~(size_t)255;
    return p;
  };
  bf16* hb    = alloc((size_t)MR * HID);
  bf16* wdkvT = alloc((size_t)LAT * HID);
  bf16* wukT  = alloc((size_t)HID * LAT);
  bf16* wkrT  = alloc((size_t)RD * HID);
  bf16* wuvT  = alloc((size_t)HID * LAT);
  bf16* wdqT  = alloc((size_t)LAT * HID);
  bf16* wuqT  = alloc((size_t)HID * LAT);
  bf16* wqrT  = alloc((size_t)(RD * NHEAD) * LAT);
  bf16* woT   = alloc((size_t)HID * HID);
  bf16* ckv   = alloc((size_t)MR * LAT);
  bf16* kc    = alloc((size_t)MR * HID);
  bf16* krr   = alloc((size_t)MR * RD);
  bf16* vflat = alloc((size_t)MR * HID);
  bf16* cq    = alloc((size_t)MR * LAT);
  bf16* qc    = alloc((size_t)MR * HID);
  bf16* qrr   = alloc((size_t)MR * RD * NHEAD);
  bf16* qbuf  = alloc((size_t)BB * NHEAD * SEQ * DQK);
  bf16* kbuf  = alloc((size_t)BB * NHEAD * SEQ * DQK);
  bf16* vt    = alloc((size_t)BB * NHEAD * HD * SEQ);
  bf16* oflat = alloc((size_t)MR * HID);
  float* cosT = (float*)alloc((size_t)SEQ * 32 * 2);
  float* sinT = (float*)alloc((size_t)SEQ * 32 * 2);

  // conversions
  k_cvt<<<MR * HID / 4 / 256, 256, 0, stream>>>(h, hb, MR * HID / 4);
  k_transpose_cvt<<<dim3(LAT / 32, HID / 32), 256, 0, stream>>>(Wdkv, wdkvT, HID, LAT);
  k_transpose_cvt<<<dim3(HID / 32, LAT / 32), 256, 0, stream>>>(Wuk, wukT, LAT, HID);
  k_transpose_cvt<<<dim3(RD / 32, HID / 32), 256, 0, stream>>>(Wkr, wkrT, HID, RD);
  k_transpose_cvt<<<dim3(HID / 32, LAT / 32), 256, 0, stream>>>(Wuv, wuvT, LAT, HID);
  k_transpose_cvt<<<dim3(LAT / 32, HID / 32), 256, 0, stream>>>(Wdq, wdqT, HID, LAT);
  k_transpose_cvt<<<dim3(HID / 32, LAT / 32), 256, 0, stream>>>(Wuq, wuqT, LAT, HID);
  k_transpose_cvt<<<dim3(RD * NHEAD / 32, LAT / 32), 256, 0, stream>>>(Wqr, wqrT, LAT, RD * NHEAD);
  k_transpose_cvt<<<dim3(HID / 32, HID / 32), 256, 0, stream>>>(Wo, woT, HID, HID);
  k_rope_tables<<<SEQ * 32 / 256, 256, 0, stream>>>(cosT, sinT);

  // projection GEMMs
  k_gemm_bt<128, 128, bf16><<<dim3(LAT / 128, MR / 128), 256, 0, stream>>>(hb, wdkvT, ckv, MR, LAT, HID);
  k_gemm_bt<128, 128, bf16><<<dim3(HID / 128, MR / 128), 256, 0, stream>>>(ckv, wukT, kc, MR, HID, LAT);
  k_gemm_bt<128, 64, bf16><<<dim3(RD / 64, MR / 128), 128, 0, stream>>>(hb, wkrT, krr, MR, RD, HID);
  k_gemm_bt<128, 128, bf16><<<dim3(HID / 128, MR / 128), 256, 0, stream>>>(ckv, wuvT, vflat, MR, HID, LAT);
  k_gemm_bt<128, 128, bf16><<<dim3(LAT / 128, MR / 128), 256, 0, stream>>>(hb, wdqT, cq, MR, LAT, HID);
  k_gemm_bt<128, 128, bf16><<<dim3(HID / 128, MR / 128), 256, 0, stream>>>(cq, wuqT, qc, MR, HID, LAT);
  k_gemm_bt<128, 128, bf16><<<dim3(RD * NHEAD / 128, MR / 128), 256, 0, stream>>>(cq, wqrT, qrr, MR, RD * NHEAD, LAT);

  // assemble attention operands
  unsigned qblocks = (unsigned)((size_t)BB * NHEAD * SEQ * DQK / 256);
  k_assemble_q<<<qblocks, 256, 0, stream>>>(qc, qrr, cosT, sinT, qbuf);
  k_assemble_k<<<qblocks, 256, 0, stream>>>(kc, krr, cosT, sinT, kbuf);
  k_transpose_v<<<dim3(HD / 32, SEQ / 32, BB * NHEAD), 256, 0, stream>>>(vflat, vt);

  // attention
  k_attn<<<dim3(SEQ / 64, BB * NHEAD), 256, 0, stream>>>(qbuf, kbuf, vt, oflat);

  // output projection (fp32 out)
  k_gemm_bt<128, 128, float><<<dim3(HID / 128, MR / 128), 256, 0, stream>>>(oflat, woT, out, MR, HID, HID);
}

// Round 2
// 674.417 us; speedup vs baseline: 1.4440x; 1.4440x over previous
//
#include <hip/hip_runtime.h>
#include <hip/hip_bf16.h>
#include <type_traits>
#include <cstdint>

typedef __bf16 bf16x8 __attribute__((ext_vector_type(8)));
typedef float f32x4 __attribute__((ext_vector_type(4)));
typedef __hip_bfloat16 bf16;

static constexpr int BB = 2, SEQ = 2048, HID = 2048, LAT = 512, NHEAD = 16;
static constexpr int HD = 128, RD = 64, DQK = 192;
static constexpr int MR = BB * SEQ;  // 4096 rows

__device__ __forceinline__ float bf2f(bf16 x) { return __bfloat162float(x); }
__device__ __forceinline__ bf16 f2bf(float x) { return __float2bfloat16(x); }

// async global->LDS, 16B per lane, dest = wave-uniform base + lane*16
__device__ __forceinline__ void gload16(const void* g, void* l) {
  __builtin_amdgcn_global_load_lds(
      (__attribute__((address_space(1))) void*)(uintptr_t)g,
      (__attribute__((address_space(3))) void*)(uint32_t)(uintptr_t)l,
      16, 0, 0);
}

// ---------------- fp32 -> bf16 elementwise ----------------
__global__ void k_cvt(const float* __restrict__ in, bf16* __restrict__ out, int n4) {
  int i = blockIdx.x * 256 + threadIdx.x;
  if (i >= n4) return;
  float4 v = reinterpret_cast<const float4*>(in)[i];
  bf16* o = out + (size_t)i * 4;
  o[0] = f2bf(v.x); o[1] = f2bf(v.y); o[2] = f2bf(v.z); o[3] = f2bf(v.w);
}

// ---------------- transpose+convert: W[K][N] f32 -> WT[N][K] bf16 ----------------
__global__ void k_transpose_cvt(const float* __restrict__ W, bf16* __restrict__ WT,
                                int K, int N) {
  __shared__ float t[32][33];
  int k0 = blockIdx.y * 32, n0 = blockIdx.x * 32;
  int c = threadIdx.x & 31, r0 = threadIdx.x >> 5;
#pragma unroll
  for (int i = 0; i < 32; i += 8) t[r0 + i][c] = W[(size_t)(k0 + r0 + i) * N + n0 + c];
  __syncthreads();
#pragma unroll
  for (int i = 0; i < 32; i += 8)
    WT[(size_t)(n0 + r0 + i) * K + k0 + c] = f2bf(t[c][r0 + i]);
}

// ---------------- V transpose: vflat[b*S+s][h*128+d] -> vt[bh][d][s] ----------------
__global__ void k_transpose_v(const bf16* __restrict__ vflat, bf16* __restrict__ vt) {
  __shared__ bf16 t[32][34];
  int bh = blockIdx.z, b = bh >> 4, hh = bh & 15;
  int s0 = blockIdx.y * 32, d0 = blockIdx.x * 32;
  int c = threadIdx.x & 31, r0 = threadIdx.x >> 5;
#pragma unroll
  for (int i = 0; i < 32; i += 8)
    t[r0 + i][c] = vflat[((size_t)b * SEQ + s0 + r0 + i) * HID + hh * HD + d0 + c];
  __syncthreads();
#pragma unroll
  for (int i = 0; i < 32; i += 8)
    vt[((size_t)bh * HD + d0 + r0 + i) * SEQ + s0 + c] = t[c][r0 + i];
}

// ---------------- RoPE tables ----------------
__global__ void k_rope_tables(float* __restrict__ cosT, float* __restrict__ sinT) {
  int idx = blockIdx.x * 256 + threadIdx.x;  // SEQ*32
  int s = idx >> 5, j = idx & 31;
  float freq = powf(10000.0f, -(float)(2 * j) / 64.0f);
  float a = (float)s * freq;
  cosT[idx] = cosf(a);
  sinT[idx] = sinf(a);
}

// ---------------- GEMM (m97 structure): C = A * BT^T ----------------
template <int BM, int BN, typename OutT>
__global__ __launch_bounds__((BM / 64) * (BN / 64) * 64)
void k_gemm_bt(const bf16* __restrict__ A, const bf16* __restrict__ BT,
               OutT* __restrict__ C, int M, int N, int K) {
  constexpr int BK = 32;
  constexpr int WN = BN / 64, NW = (BM / 64) * WN;
  __shared__ alignas(16) bf16 As[BM * BK];
  __shared__ alignas(16) bf16 Bs[BN * BK];
  const int tid = threadIdx.x, wave = tid >> 6, lane = tid & 63;
  const int lr = lane & 15, lk = lane >> 4;
  const int wm = (wave / WN) * 64, wn = (wave % WN) * 64;
  const int m0 = blockIdx.y * BM, n0 = blockIdx.x * BN;
  const int srow = lane >> 2;        // row within 16-row chunk
  const int scol = (lane & 3) * 8;   // elem col within row (4 x 16B per 64B row)
  f32x4 acc[4][4] = {};
  for (int kt = 0; kt < K; kt += BK) {
    for (int c = wave; c < BM / 16; c += NW)
      gload16(A + (size_t)(m0 + c * 16 + srow) * K + kt + scol, (char*)As + c * 1024);
    for (int c = wave; c < BN / 16; c += NW)
      gload16(BT + (size_t)(n0 + c * 16 + srow) * K + kt + scol, (char*)Bs + c * 1024);
    __syncthreads();
    bf16x8 af[4], bfr[4];
#pragma unroll
    for (int i = 0; i < 4; i++)
      af[i] = *reinterpret_cast<const bf16x8*>(As + (wm + i * 16 + lr) * BK + lk * 8);
#pragma unroll
    for (int j = 0; j < 4; j++)
      bfr[j] = *reinterpret_cast<const bf16x8*>(Bs + (wn + j * 16 + lr) * BK + lk * 8);
#pragma unroll
    for (int i = 0; i < 4; i++)
#pragma unroll
      for (int j = 0; j < 4; j++)
        acc[i][j] = __builtin_amdgcn_mfma_f32_16x16x32_bf16(af[i], bfr[j], acc[i][j], 0, 0, 0);
    __syncthreads();
  }
#pragma unroll
  for (int i = 0; i < 4; i++)
#pragma unroll
    for (int j = 0; j < 4; j++) {
      int row = m0 + wm + i * 16 + lk * 4, col = n0 + wn + j * 16 + lr;
#pragma unroll
      for (int r = 0; r < 4; r++) {
        float v = acc[i][j][r];
        if constexpr (std::is_same<OutT, float>::value)
          C[(size_t)(row + r) * N + col] = v;
        else
          C[(size_t)(row + r) * N + col] = f2bf(v);
      }
    }
}

// ---------------- assemble q / k (concat + RoPE) ----------------
__global__ void k_assemble_q(const bf16* __restrict__ qc, const bf16* __restrict__ qrr,
                             const float* __restrict__ cosT, const float* __restrict__ sinT,
                             bf16* __restrict__ qbuf) {
  size_t idx = (size_t)blockIdx.x * 256 + threadIdx.x;
  int d = (int)(idx % DQK);
  size_t t = idx / DQK;
  int s = (int)(t % SEQ); t /= SEQ;
  int hh = (int)(t % NHEAD);
  int b = (int)(t / NHEAD);
  size_t row = (size_t)b * SEQ + s;
  bf16 v;
  if (d < HD) {
    v = qc[row * HID + hh * HD + d];
  } else {
    int dd = d - HD, j = dd >> 1;
    float cs = cosT[s * 32 + j], sn = sinT[s * 32 + j];
    float x0 = bf2f(qrr[row * (RD * NHEAD) + hh * RD + 2 * j]);
    float x1 = bf2f(qrr[row * (RD * NHEAD) + hh * RD + 2 * j + 1]);
    v = f2bf((dd & 1) ? (x1 * cs + x0 * sn) : (x0 * cs - x1 * sn));
  }
  qbuf[idx] = v;
}

__global__ void k_assemble_k(const bf16* __restrict__ kc, const bf16* __restrict__ krr,
                             const float* __restrict__ cosT, const float* __restrict__ sinT,
                             bf16* __restrict__ kbuf) {
  size_t idx = (size_t)blockIdx.x * 256 + threadIdx.x;
  int d = (int)(idx % DQK);
  size_t t = idx / DQK;
  int s = (int)(t % SEQ); t /= SEQ;
  int hh = (int)(t % NHEAD);
  int b = (int)(t / NHEAD);
  size_t row = (size_t)b * SEQ + s;
  bf16 v;
  if (d < HD) {
    v = kc[row * HID + hh * HD + d];
  } else {
    int dd = d - HD, j = dd >> 1;
    float cs = cosT[s * 32 + j], sn = sinT[s * 32 + j];
    float x0 = bf2f(krr[row * RD + 2 * j]);
    float x1 = bf2f(krr[row * RD + 2 * j + 1]);
    v = f2bf((dd & 1) ? (x1 * cs + x0 * sn) : (x0 * cs - x1 * sn));
  }
  kbuf[idx] = v;
}

// ---------------- causal flash attention (swizzled LDS, 2 barriers/tile) ----------------
// Q,K: [bh][S][192]; VT: [bh][128][S]; Of: [b*S+s][h*128+d] all bf16
// LDS layouts (16B "slots"): phys_slot = logical_slot ^ (row & 7), rows linear.
__global__ __launch_bounds__(256)
void k_attn(const bf16* __restrict__ Q, const bf16* __restrict__ Kb,
            const bf16* __restrict__ VT, bf16* __restrict__ Of) {
  constexpr int QB = 64, KBL = 64;
  __shared__ alignas(16) bf16 Ks[KBL * DQK];      // 24576 B, 24 slots/row
  __shared__ alignas(16) bf16 Vs[HD * KBL];       // 16384 B, 8 slots/row
  __shared__ alignas(16) bf16 Ps[4 * 16 * KBL];   // 8192 B, per-wave 16x64
  const int qt = blockIdx.x, bh = blockIdx.y;
  const int b = bh >> 4, hh = bh & 15;
  const int tid = threadIdx.x, wave = tid >> 6, lane = tid & 63;
  const int lr = lane & 15, lk = lane >> 4;
  const int q0 = qt * QB;
  const float scale = 0.07216878364870323f;  // 1/sqrt(192)

  const bf16* Qp = Q + ((size_t)bh * SEQ + q0 + wave * 16 + lr) * DQK;
  bf16x8 qf[6];
#pragma unroll
  for (int c = 0; c < 6; c++)
    qf[c] = *reinterpret_cast<const bf16x8*>(Qp + c * 32 + lk * 8);

  bf16* PsW = Ps + wave * (16 * KBL);

  f32x4 oacc[8] = {};
  float mrow[4], lrow[4];
#pragma unroll
  for (int r = 0; r < 4; r++) { mrow[r] = -INFINITY; lrow[r] = 0.f; }

  for (int kt = 0; kt <= qt; kt++) {
    const int k0 = kt * KBL;
    const bf16* Kbase = Kb + ((size_t)bh * SEQ + k0) * DQK;
    const bf16* Vbase = VT + (size_t)bh * HD * SEQ + k0;
    // K tile: 64 rows x 384B contiguous; pre-swizzled source, linear dest
    for (int c = wave; c < 24; c += 4) {
      int S = c * 64 + lane;
      int row = S / 24;
      int scl = (S - row * 24) ^ (row & 7);
      gload16(Kbase + row * DQK + scl * 8, (char*)Ks + c * 1024);
    }
    // V tile: 128 rows x 128B (row stride SEQ)
    for (int c = wave; c < 16; c += 4) {
      int S = c * 64 + lane;
      int row = S >> 3;
      int scl = (S & 7) ^ (row & 7);
      gload16(Vbase + (size_t)row * SEQ + scl * 8, (char*)Vs + c * 1024);
    }
    __syncthreads();

    f32x4 sc[4] = {};
#pragma unroll
    for (int cb = 0; cb < 4; cb++) {
      const int krow = cb * 16 + lr;
#pragma unroll
      for (int c = 0; c < 6; c++) {
        int phys = (c * 4 + lk) ^ (krow & 7);
        bf16x8 kf = *reinterpret_cast<const bf16x8*>(Ks + krow * DQK + phys * 8);
        sc[cb] = __builtin_amdgcn_mfma_f32_16x16x32_bf16(qf[c], kf, sc[cb], 0, 0, 0);
      }
    }

    const bool maskit = (kt == qt);
    float p[4][4], tm[4];
#pragma unroll
    for (int r = 0; r < 4; r++) tm[r] = -INFINITY;
#pragma unroll
    for (int cb = 0; cb < 4; cb++) {
      const int kcg = k0 + cb * 16 + lr;
#pragma unroll
      for (int r = 0; r < 4; r++) {
        float v = sc[cb][r] * scale;
        if (maskit && kcg > q0 + wave * 16 + lk * 4 + r) v = -INFINITY;
        p[cb][r] = v;
        tm[r] = fmaxf(tm[r], v);
      }
    }
#pragma unroll
    for (int m = 1; m < 16; m <<= 1)
#pragma unroll
      for (int r = 0; r < 4; r++) tm[r] = fmaxf(tm[r], __shfl_xor(tm[r], m, 16));

    float rs[4];
#pragma unroll
    for (int r = 0; r < 4; r++) {
      float mn = fmaxf(mrow[r], tm[r]);
      float al = __expf(mrow[r] - mn);
      mrow[r] = mn;
      lrow[r] *= al;
#pragma unroll
      for (int ocb = 0; ocb < 8; ocb++) oacc[ocb][r] *= al;
      float ssum = 0.f;
#pragma unroll
      for (int cb = 0; cb < 4; cb++) {
        float e = __expf(p[cb][r] - mn);
        p[cb][r] = e;
        ssum += e;
      }
      rs[r] = ssum;
    }
#pragma unroll
    for (int m = 1; m < 16; m <<= 1)
#pragma unroll
      for (int r = 0; r < 4; r++) rs[r] += __shfl_xor(rs[r], m, 16);
#pragma unroll
    for (int r = 0; r < 4; r++) lrow[r] += rs[r];

    // P -> LDS (wave-private, swizzled); no block barrier needed
#pragma unroll
    for (int cb = 0; cb < 4; cb++)
#pragma unroll
      for (int r = 0; r < 4; r++) {
        int prow = lk * 4 + r;
        int pslot = (cb * 2 + (lr >> 3)) ^ (prow & 7);
        PsW[prow * KBL + pslot * 8 + (lr & 7)] = f2bf(p[cb][r]);
      }

#pragma unroll
    for (int kk = 0; kk < 2; kk++) {
      int pphys = (kk * 4 + lk) ^ (lr & 7);
      bf16x8 pa = *reinterpret_cast<const bf16x8*>(PsW + lr * KBL + pphys * 8);
#pragma unroll
      for (int ocb = 0; ocb < 8; ocb++) {
        int vrow = ocb * 16 + lr;
        int vphys = (kk * 4 + lk) ^ (vrow & 7);
        bf16x8 vb = *reinterpret_cast<const bf16x8*>(Vs + vrow * KBL + vphys * 8);
        oacc[ocb] = __builtin_amdgcn_mfma_f32_16x16x32_bf16(pa, vb, oacc[ocb], 0, 0, 0);
      }
    }
    __syncthreads();
  }

#pragma unroll
  for (int ocb = 0; ocb < 8; ocb++)
#pragma unroll
    for (int r = 0; r < 4; r++) {
      int qr = q0 + wave * 16 + lk * 4 + r;
      float v = oacc[ocb][r] / lrow[r];
      Of[((size_t)b * SEQ + qr) * HID + hh * HD + ocb * 16 + lr] = f2bf(v);
    }
}

// ---------------- host launch ----------------
extern "C" void kernel_launch(void* const* d_in, const int* in_sizes, int n_in,
                              void* d_out, int out_size, void* d_ws, size_t ws_size,
                              hipStream_t stream) {
  const float* h    = (const float*)d_in[0];
  const float* Wdkv = (const float*)d_in[1];
  const float* Wuk  = (const float*)d_in[2];
  const float* Wkr  = (const float*)d_in[3];
  const float* Wuv  = (const float*)d_in[4];
  const float* Wdq  = (const float*)d_in[5];
  const float* Wuq  = (const float*)d_in[6];
  const float* Wqr  = (const float*)d_in[7];
  const float* Wo   = (const float*)d_in[8];
  float* out = (float*)d_out;

  char* w = (char*)d_ws;
  auto alloc = [&](size_t elems) {
    bf16* p = (bf16*)w;
    w += (elems * sizeof(bf16) + 255) & ~(size_t)255;
    return p;
  };
  bf16* hb    = alloc((size_t)MR * HID);
  bf16* wdkvT = alloc((size_t)LAT * HID);
  bf16* wukT  = alloc((size_t)HID * LAT);
  bf16* wkrT  = alloc((size_t)RD * HID);
  bf16* wuvT  = alloc((size_t)HID * LAT);
  bf16* wdqT  = alloc((size_t)LAT * HID);
  bf16* wuqT  = alloc((size_t)HID * LAT);
  bf16* wqrT  = alloc((size_t)(RD * NHEAD) * LAT);
  bf16* woT   = alloc((size_t)HID * HID);
  bf16* ckv   = alloc((size_t)MR * LAT);
  bf16* kc    = alloc((size_t)MR * HID);
  bf16* krr   = alloc((size_t)MR * RD);
  bf16* vflat = alloc((size_t)MR * HID);
  bf16* cq    = alloc((size_t)MR * LAT);
  bf16* qc    = alloc((size_t)MR * HID);
  bf16* qrr   = alloc((size_t)MR * RD * NHEAD);
  bf16* qbuf  = alloc((size_t)BB * NHEAD * SEQ * DQK);
  bf16* kbuf  = alloc((size_t)BB * NHEAD * SEQ * DQK);
  bf16* vt    = alloc((size_t)BB * NHEAD * HD * SEQ);
  bf16* oflat = alloc((size_t)MR * HID);
  float* cosT = (float*)alloc((size_t)SEQ * 32 * 2);
  float* sinT = (float*)alloc((size_t)SEQ * 32 * 2);

  // conversions
  k_cvt<<<MR * HID / 4 / 256, 256, 0, stream>>>(h, hb, MR * HID / 4);
  k_transpose_cvt<<<dim3(LAT / 32, HID / 32), 256, 0, stream>>>(Wdkv, wdkvT, HID, LAT);
  k_transpose_cvt<<<dim3(HID / 32, LAT / 32), 256, 0, stream>>>(Wuk, wukT, LAT, HID);
  k_transpose_cvt<<<dim3(RD / 32, HID / 32), 256, 0, stream>>>(Wkr, wkrT, HID, RD);
  k_transpose_cvt<<<dim3(HID / 32, LAT / 32), 256, 0, stream>>>(Wuv, wuvT, LAT, HID);
  k_transpose_cvt<<<dim3(LAT / 32, HID / 32), 256, 0, stream>>>(Wdq, wdqT, HID, LAT);
  k_transpose_cvt<<<dim3(HID / 32, LAT / 32), 256, 0, stream>>>(Wuq, wuqT, LAT, HID);
  k_transpose_cvt<<<dim3(RD * NHEAD / 32, LAT / 32), 256, 0, stream>>>(Wqr, wqrT, LAT, RD * NHEAD);
  k_transpose_cvt<<<dim3(HID / 32, HID / 32), 256, 0, stream>>>(Wo, woT, HID, HID);
  k_rope_tables<<<SEQ * 32 / 256, 256, 0, stream>>>(cosT, sinT);

  // projection GEMMs
  k_gemm_bt<128, 128, bf16><<<dim3(LAT / 128, MR / 128), 256, 0, stream>>>(hb, wdkvT, ckv, MR, LAT, HID);
  k_gemm_bt<128, 128, bf16><<<dim3(HID / 128, MR / 128), 256, 0, stream>>>(ckv, wukT, kc, MR, HID, LAT);
  k_gemm_bt<128, 64, bf16><<<dim3(RD / 64, MR / 128), 128, 0, stream>>>(hb, wkrT, krr, MR, RD, HID);
  k_gemm_bt<128, 128, bf16><<<dim3(HID / 128, MR / 128), 256, 0, stream>>>(ckv, wuvT, vflat, MR, HID, LAT);
  k_gemm_bt<128, 128, bf16><<<dim3(LAT / 128, MR / 128), 256, 0, stream>>>(hb, wdqT, cq, MR, LAT, HID);
  k_gemm_bt<128, 128, bf16><<<dim3(HID / 128, MR / 128), 256, 0, stream>>>(cq, wuqT, qc, MR, HID, LAT);
  k_gemm_bt<128, 128, bf16><<<dim3(RD * NHEAD / 128, MR / 128), 256, 0, stream>>>(cq, wqrT, qrr, MR, RD * NHEAD, LAT);

  // assemble attention operands
  unsigned qblocks = (unsigned)((size_t)BB * NHEAD * SEQ * DQK / 256);
  k_assemble_q<<<qblocks, 256, 0, stream>>>(qc, qrr, cosT, sinT, qbuf);
  k_assemble_k<<<qblocks, 256, 0, stream>>>(kc, krr, cosT, sinT, kbuf);
  k_transpose_v<<<dim3(HD / 32, SEQ / 32, BB * NHEAD), 256, 0, stream>>>(vflat, vt);

  // attention
  k_attn<<<dim3(SEQ / 64, BB * NHEAD), 256, 0, stream>>>(qbuf, kbuf, vt, oflat);

  // output projection (fp32 out)
  k_gemm_bt<128, 128, float><<<dim3(HID / 128, MR / 128), 256, 0, stream>>>(oflat, woT, out, MR, HID, HID);
}

// Round 3
// 469.957 us; speedup vs baseline: 2.0722x; 1.4351x over previous
//
#include <hip/hip_runtime.h>
#include <hip/hip_bf16.h>
#include <type_traits>
#include <cstdint>

typedef __bf16 bf16x8 __attribute__((ext_vector_type(8)));
typedef float f32x4 __attribute__((ext_vector_type(4)));
typedef __hip_bfloat16 bf16;

static constexpr int BB = 2, SEQ = 2048, HID = 2048, LAT = 512, NHEAD = 16;
static constexpr int HD = 128, RD = 64, DQK = 192;
static constexpr int MR = BB * SEQ;  // 4096 rows
static constexpr int LDW1 = 1152;    // fused proj-1 output cols (1088 padded to 9*128)
static constexpr int LDKV = 4096;    // fused kv output cols
static constexpr int LDQ3 = 3072;    // fused q output cols

__device__ __forceinline__ float bf2f(bf16 x) { return __bfloat162float(x); }
__device__ __forceinline__ bf16 f2bf(float x) { return __float2bfloat16(x); }

// async global->LDS, 16B per lane, dest = wave-uniform base + lane*16
__device__ __forceinline__ void gload16(const void* g, void* l) {
  __builtin_amdgcn_global_load_lds(
      (__attribute__((address_space(1))) void*)(uintptr_t)g,
      (__attribute__((address_space(3))) void*)(uint32_t)(uintptr_t)l,
      16, 0, 0);
}

// ---------------- fp32 -> bf16 elementwise ----------------
__global__ void k_cvt(const float* __restrict__ in, bf16* __restrict__ out, int n4) {
  int i = blockIdx.x * 256 + threadIdx.x;
  if (i >= n4) return;
  float4 v = reinterpret_cast<const float4*>(in)[i];
  bf16* o = out + (size_t)i * 4;
  o[0] = f2bf(v.x); o[1] = f2bf(v.y); o[2] = f2bf(v.z); o[3] = f2bf(v.w);
}

// ---------------- transpose+convert: W[K][N] f32 -> WT[N][K] bf16 ----------------
__global__ void k_transpose_cvt(const float* __restrict__ W, bf16* __restrict__ WT,
                                int K, int N) {
  __shared__ float t[32][33];
  int k0 = blockIdx.y * 32, n0 = blockIdx.x * 32;
  int c = threadIdx.x & 31, r0 = threadIdx.x >> 5;
#pragma unroll
  for (int i = 0; i < 32; i += 8) t[r0 + i][c] = W[(size_t)(k0 + r0 + i) * N + n0 + c];
  __syncthreads();
#pragma unroll
  for (int i = 0; i < 32; i += 8)
    WT[(size_t)(n0 + r0 + i) * K + k0 + c] = f2bf(t[c][r0 + i]);
}

// ---------------- V transpose: kv[b*S+s][2048 + h*128+d] -> vt[bh][d][s] ----------------
__global__ void k_transpose_v(const bf16* __restrict__ kv, bf16* __restrict__ vt) {
  __shared__ bf16 t[32][34];
  int bh = blockIdx.z, b = bh >> 4, hh = bh & 15;
  int s0 = blockIdx.y * 32, d0 = blockIdx.x * 32;
  int c = threadIdx.x & 31, r0 = threadIdx.x >> 5;
#pragma unroll
  for (int i = 0; i < 32; i += 8)
    t[r0 + i][c] = kv[((size_t)b * SEQ + s0 + r0 + i) * LDKV + HID + hh * HD + d0 + c];
  __syncthreads();
#pragma unroll
  for (int i = 0; i < 32; i += 8)
    vt[((size_t)bh * HD + d0 + r0 + i) * SEQ + s0 + c] = t[c][r0 + i];
}

// ---------------- RoPE tables ----------------
__global__ void k_rope_tables(float* __restrict__ cosT, float* __restrict__ sinT) {
  int idx = blockIdx.x * 256 + threadIdx.x;  // SEQ*32
  int s = idx >> 5, j = idx & 31;
  float freq = powf(10000.0f, -(float)(2 * j) / 64.0f);
  float a = (float)s * freq;
  cosT[idx] = cosf(a);
  sinT[idx] = sinf(a);
}

// ---------------- GEMM (m97 structure): C = A * BT^T, strided A/C ----------------
template <int BM, int BN, typename OutT>
__global__ __launch_bounds__((BM / 64) * (BN / 64) * 64)
void k_gemm_bt(const bf16* __restrict__ A, int lda, const bf16* __restrict__ BT,
               OutT* __restrict__ C, int ldc, int M, int N, int K) {
  constexpr int BK = 32;
  constexpr int WN = BN / 64, NW = (BM / 64) * WN;
  __shared__ alignas(16) bf16 As[BM * BK];
  __shared__ alignas(16) bf16 Bs[BN * BK];
  const int tid = threadIdx.x, wave = tid >> 6, lane = tid & 63;
  const int lr = lane & 15, lk = lane >> 4;
  const int wm = (wave / WN) * 64, wn = (wave % WN) * 64;
  const int m0 = blockIdx.y * BM, n0 = blockIdx.x * BN;
  const int srow = lane >> 2;
  const int scol = (lane & 3) * 8;
  f32x4 acc[4][4] = {};
  for (int kt = 0; kt < K; kt += BK) {
    for (int c = wave; c < BM / 16; c += NW)
      gload16(A + (size_t)(m0 + c * 16 + srow) * lda + kt + scol, (char*)As + c * 1024);
    for (int c = wave; c < BN / 16; c += NW)
      gload16(BT + (size_t)(n0 + c * 16 + srow) * K + kt + scol, (char*)Bs + c * 1024);
    __syncthreads();
    bf16x8 af[4], bfr[4];
#pragma unroll
    for (int i = 0; i < 4; i++)
      af[i] = *reinterpret_cast<const bf16x8*>(As + (wm + i * 16 + lr) * BK + lk * 8);
#pragma unroll
    for (int j = 0; j < 4; j++)
      bfr[j] = *reinterpret_cast<const bf16x8*>(Bs + (wn + j * 16 + lr) * BK + lk * 8);
    __builtin_amdgcn_s_setprio(1);
#pragma unroll
    for (int i = 0; i < 4; i++)
#pragma unroll
      for (int j = 0; j < 4; j++)
        acc[i][j] = __builtin_amdgcn_mfma_f32_16x16x32_bf16(af[i], bfr[j], acc[i][j], 0, 0, 0);
    __builtin_amdgcn_s_setprio(0);
    __syncthreads();
  }
#pragma unroll
  for (int i = 0; i < 4; i++)
#pragma unroll
    for (int j = 0; j < 4; j++) {
      int row = m0 + wm + i * 16 + lk * 4, col = n0 + wn + j * 16 + lr;
#pragma unroll
      for (int r = 0; r < 4; r++) {
        float v = acc[i][j][r];
        if constexpr (std::is_same<OutT, float>::value)
          C[(size_t)(row + r) * ldc + col] = v;
        else
          C[(size_t)(row + r) * ldc + col] = f2bf(v);
      }
    }
}

// ---------------- assemble q / k (concat + RoPE) ----------------
__global__ void k_assemble_q(const bf16* __restrict__ q3,
                             const float* __restrict__ cosT, const float* __restrict__ sinT,
                             bf16* __restrict__ qbuf) {
  size_t idx = (size_t)blockIdx.x * 256 + threadIdx.x;
  int d = (int)(idx % DQK);
  size_t t = idx / DQK;
  int s = (int)(t % SEQ); t /= SEQ;
  int hh = (int)(t % NHEAD);
  int b = (int)(t / NHEAD);
  size_t row = (size_t)b * SEQ + s;
  bf16 v;
  if (d < HD) {
    v = q3[row * LDQ3 + hh * HD + d];
  } else {
    int dd = d - HD, j = dd >> 1;
    float cs = cosT[s * 32 + j], sn = sinT[s * 32 + j];
    float x0 = bf2f(q3[row * LDQ3 + HID + hh * RD + 2 * j]);
    float x1 = bf2f(q3[row * LDQ3 + HID + hh * RD + 2 * j + 1]);
    v = f2bf((dd & 1) ? (x1 * cs + x0 * sn) : (x0 * cs - x1 * sn));
  }
  qbuf[idx] = v;
}

__global__ void k_assemble_k(const bf16* __restrict__ kv, const bf16* __restrict__ out1,
                             const float* __restrict__ cosT, const float* __restrict__ sinT,
                             bf16* __restrict__ kbuf) {
  size_t idx = (size_t)blockIdx.x * 256 + threadIdx.x;
  int d = (int)(idx % DQK);
  size_t t = idx / DQK;
  int s = (int)(t % SEQ); t /= SEQ;
  int hh = (int)(t % NHEAD);
  int b = (int)(t / NHEAD);
  size_t row = (size_t)b * SEQ + s;
  bf16 v;
  if (d < HD) {
    v = kv[row * LDKV + hh * HD + d];
  } else {
    int dd = d - HD, j = dd >> 1;
    float cs = cosT[s * 32 + j], sn = sinT[s * 32 + j];
    float x0 = bf2f(out1[row * LDW1 + 1024 + 2 * j]);
    float x1 = bf2f(out1[row * LDW1 + 1024 + 2 * j + 1]);
    v = f2bf((dd & 1) ? (x1 * cs + x0 * sn) : (x0 * cs - x1 * sn));
  }
  kbuf[idx] = v;
}

// ---------------- causal flash attention (swizzled LDS, longest-first) ----------------
__global__ __launch_bounds__(256)
void k_attn(const bf16* __restrict__ Q, const bf16* __restrict__ Kb,
            const bf16* __restrict__ VT, bf16* __restrict__ Of) {
  constexpr int QB = 64, KBL = 64;
  __shared__ alignas(16) bf16 Ks[KBL * DQK];      // 24576 B, 24 slots/row
  __shared__ alignas(16) bf16 Vs[HD * KBL];       // 16384 B, 8 slots/row
  __shared__ alignas(16) bf16 Ps[4 * 16 * KBL];   // 8192 B
  const int qt = (SEQ / QB - 1) - (blockIdx.x >> 5);  // longest-first
  const int bh = blockIdx.x & 31;
  const int b = bh >> 4, hh = bh & 15;
  const int tid = threadIdx.x, wave = tid >> 6, lane = tid & 63;
  const int lr = lane & 15, lk = lane >> 4;
  const int q0 = qt * QB;
  const float scale = 0.07216878364870323f;  // 1/sqrt(192)

  const bf16* Qp = Q + ((size_t)bh * SEQ + q0 + wave * 16 + lr) * DQK;
  bf16x8 qf[6];
#pragma unroll
  for (int c = 0; c < 6; c++)
    qf[c] = *reinterpret_cast<const bf16x8*>(Qp + c * 32 + lk * 8);

  bf16* PsW = Ps + wave * (16 * KBL);

  f32x4 oacc[8] = {};
  float mrow[4], lrow[4];
#pragma unroll
  for (int r = 0; r < 4; r++) { mrow[r] = -INFINITY; lrow[r] = 0.f; }

  for (int kt = 0; kt <= qt; kt++) {
    const int k0 = kt * KBL;
    const bf16* Kbase = Kb + ((size_t)bh * SEQ + k0) * DQK;
    const bf16* Vbase = VT + (size_t)bh * HD * SEQ + k0;
    for (int c = wave; c < 24; c += 4) {
      int S = c * 64 + lane;
      int row = S / 24;
      int scl = (S - row * 24) ^ (row & 7);
      gload16(Kbase + row * DQK + scl * 8, (char*)Ks + c * 1024);
    }
    for (int c = wave; c < 16; c += 4) {
      int S = c * 64 + lane;
      int row = S >> 3;
      int scl = (S & 7) ^ (row & 7);
      gload16(Vbase + (size_t)row * SEQ + scl * 8, (char*)Vs + c * 1024);
    }
    __syncthreads();

    f32x4 sc[4] = {};
    __builtin_amdgcn_s_setprio(1);
#pragma unroll
    for (int cb = 0; cb < 4; cb++) {
      const int krow = cb * 16 + lr;
#pragma unroll
      for (int c = 0; c < 6; c++) {
        int phys = (c * 4 + lk) ^ (krow & 7);
        bf16x8 kf = *reinterpret_cast<const bf16x8*>(Ks + krow * DQK + phys * 8);
        sc[cb] = __builtin_amdgcn_mfma_f32_16x16x32_bf16(qf[c], kf, sc[cb], 0, 0, 0);
      }
    }
    __builtin_amdgcn_s_setprio(0);

    const bool maskit = (kt == qt);
    float p[4][4], tm[4];
#pragma unroll
    for (int r = 0; r < 4; r++) tm[r] = -INFINITY;
#pragma unroll
    for (int cb = 0; cb < 4; cb++) {
      const int kcg = k0 + cb * 16 + lr;
#pragma unroll
      for (int r = 0; r < 4; r++) {
        float v = sc[cb][r] * scale;
        if (maskit && kcg > q0 + wave * 16 + lk * 4 + r) v = -INFINITY;
        p[cb][r] = v;
        tm[r] = fmaxf(tm[r], v);
      }
    }
#pragma unroll
    for (int m = 1; m < 16; m <<= 1)
#pragma unroll
      for (int r = 0; r < 4; r++) tm[r] = fmaxf(tm[r], __shfl_xor(tm[r], m, 16));

    float rs[4];
#pragma unroll
    for (int r = 0; r < 4; r++) {
      float mn = fmaxf(mrow[r], tm[r]);
      float al = __expf(mrow[r] - mn);
      mrow[r] = mn;
      lrow[r] *= al;
#pragma unroll
      for (int ocb = 0; ocb < 8; ocb++) oacc[ocb][r] *= al;
      float ssum = 0.f;
#pragma unroll
      for (int cb = 0; cb < 4; cb++) {
        float e = __expf(p[cb][r] - mn);
        p[cb][r] = e;
        ssum += e;
      }
      rs[r] = ssum;
    }
#pragma unroll
    for (int m = 1; m < 16; m <<= 1)
#pragma unroll
      for (int r = 0; r < 4; r++) rs[r] += __shfl_xor(rs[r], m, 16);
#pragma unroll
    for (int r = 0; r < 4; r++) lrow[r] += rs[r];

#pragma unroll
    for (int cb = 0; cb < 4; cb++)
#pragma unroll
      for (int r = 0; r < 4; r++) {
        int prow = lk * 4 + r;
        int pslot = (cb * 2 + (lr >> 3)) ^ (prow & 7);
        PsW[prow * KBL + pslot * 8 + (lr & 7)] = f2bf(p[cb][r]);
      }

    __builtin_amdgcn_s_setprio(1);
#pragma unroll
    for (int kk = 0; kk < 2; kk++) {
      int pphys = (kk * 4 + lk) ^ (lr & 7);
      bf16x8 pa = *reinterpret_cast<const bf16x8*>(PsW + lr * KBL + pphys * 8);
#pragma unroll
      for (int ocb = 0; ocb < 8; ocb++) {
        int vrow = ocb * 16 + lr;
        int vphys = (kk * 4 + lk) ^ (vrow & 7);
        bf16x8 vb = *reinterpret_cast<const bf16x8*>(Vs + vrow * KBL + vphys * 8);
        oacc[ocb] = __builtin_amdgcn_mfma_f32_16x16x32_bf16(pa, vb, oacc[ocb], 0, 0, 0);
      }
    }
    __builtin_amdgcn_s_setprio(0);
    __syncthreads();
  }

#pragma unroll
  for (int ocb = 0; ocb < 8; ocb++)
#pragma unroll
    for (int r = 0; r < 4; r++) {
      int qr = q0 + wave * 16 + lk * 4 + r;
      float v = oacc[ocb][r] / lrow[r];
      Of[((size_t)b * SEQ + qr) * HID + hh * HD + ocb * 16 + lr] = f2bf(v);
    }
}

// ---------------- host launch ----------------
extern "C" void kernel_launch(void* const* d_in, const int* in_sizes, int n_in,
                              void* d_out, int out_size, void* d_ws, size_t ws_size,
                              hipStream_t stream) {
  const float* h    = (const float*)d_in[0];
  const float* Wdkv = (const float*)d_in[1];
  const float* Wuk  = (const float*)d_in[2];
  const float* Wkr  = (const float*)d_in[3];
  const float* Wuv  = (const float*)d_in[4];
  const float* Wdq  = (const float*)d_in[5];
  const float* Wuq  = (const float*)d_in[6];
  const float* Wqr  = (const float*)d_in[7];
  const float* Wo   = (const float*)d_in[8];
  float* out = (float*)d_out;

  char* w = (char*)d_ws;
  auto alloc = [&](size_t elems) {
    bf16* p = (bf16*)w;
    w += (elems * sizeof(bf16) + 255) & ~(size_t)255;
    return p;
  };
  bf16* hb   = alloc((size_t)MR * HID);
  bf16* wt1  = alloc((size_t)LDW1 * HID);       // [dkv|dq|kr|pad] x 2048
  bf16* wt2  = alloc((size_t)LDKV * LAT);       // [uk|uv] x 512
  bf16* wt3  = alloc((size_t)LDQ3 * LAT);       // [uq|qr] x 512
  bf16* woT  = alloc((size_t)HID * HID);
  bf16* out1 = alloc((size_t)MR * LDW1);        // [ckv|cq|krr|pad]
  bf16* kv   = alloc((size_t)MR * LDKV);        // [k_C|v]
  bf16* q3   = alloc((size_t)MR * LDQ3);        // [q_C|q_R]
  bf16* qbuf = alloc((size_t)BB * NHEAD * SEQ * DQK);
  bf16* kbuf = alloc((size_t)BB * NHEAD * SEQ * DQK);
  bf16* vt   = alloc((size_t)BB * NHEAD * HD * SEQ);
  bf16* oflat= alloc((size_t)MR * HID);
  float* cosT = (float*)alloc((size_t)SEQ * 32 * 2);
  float* sinT = (float*)alloc((size_t)SEQ * 32 * 2);

  // conversions / weight packing
  k_cvt<<<MR * HID / 4 / 256, 256, 0, stream>>>(h, hb, MR * HID / 4);
  k_transpose_cvt<<<dim3(512 / 32, HID / 32), 256, 0, stream>>>(Wdkv, wt1, HID, 512);
  k_transpose_cvt<<<dim3(512 / 32, HID / 32), 256, 0, stream>>>(Wdq, wt1 + (size_t)512 * HID, HID, 512);
  k_transpose_cvt<<<dim3(RD / 32, HID / 32), 256, 0, stream>>>(Wkr, wt1 + (size_t)1024 * HID, HID, RD);
  k_transpose_cvt<<<dim3(HID / 32, LAT / 32), 256, 0, stream>>>(Wuk, wt2, LAT, HID);
  k_transpose_cvt<<<dim3(HID / 32, LAT / 32), 256, 0, stream>>>(Wuv, wt2 + (size_t)HID * LAT, LAT, HID);
  k_transpose_cvt<<<dim3(HID / 32, LAT / 32), 256, 0, stream>>>(Wuq, wt3, LAT, HID);
  k_transpose_cvt<<<dim3(RD * NHEAD / 32, LAT / 32), 256, 0, stream>>>(Wqr, wt3 + (size_t)HID * LAT, LAT, RD * NHEAD);
  k_transpose_cvt<<<dim3(HID / 32, HID / 32), 256, 0, stream>>>(Wo, woT, HID, HID);
  k_rope_tables<<<SEQ * 32 / 256, 256, 0, stream>>>(cosT, sinT);

  // fused projection GEMMs
  k_gemm_bt<128, 128, bf16><<<dim3(LDW1 / 128, MR / 128), 256, 0, stream>>>(hb, HID, wt1, out1, LDW1, MR, LDW1, HID);
  k_gemm_bt<128, 128, bf16><<<dim3(LDKV / 128, MR / 128), 256, 0, stream>>>(out1, LDW1, wt2, kv, LDKV, MR, LDKV, LAT);
  k_gemm_bt<128, 128, bf16><<<dim3(LDQ3 / 128, MR / 128), 256, 0, stream>>>(out1 + 512, LDW1, wt3, q3, LDQ3, MR, LDQ3, LAT);

  // assemble attention operands
  unsigned qblocks = (unsigned)((size_t)BB * NHEAD * SEQ * DQK / 256);
  k_assemble_q<<<qblocks, 256, 0, stream>>>(q3, cosT, sinT, qbuf);
  k_assemble_k<<<qblocks, 256, 0, stream>>>(kv, out1, cosT, sinT, kbuf);
  k_transpose_v<<<dim3(HD / 32, SEQ / 32, BB * NHEAD), 256, 0, stream>>>(kv, vt);

  // attention (longest-first 1D grid)
  k_attn<<<(SEQ / 64) * 32, 256, 0, stream>>>(qbuf, kbuf, vt, oflat);

  // output projection (fp32 out)
  k_gemm_bt<128, 128, float><<<dim3(HID / 128, MR / 128), 256, 0, stream>>>(oflat, HID, woT, out, HID, MR, HID, HID);
}